// Round 4
// baseline (1293.586 us; speedup 1.0000x reference)
//
#include <hip/hip_runtime.h>
#include <math.h>

#define S 32
#define T 32
#define B 64
#define H 256
#define MSZ 65536   // elements per swizzled bf16 matrix [8 kt][256 col][32 kk]
#define ROWSP 16

typedef __attribute__((ext_vector_type(8))) short s16x8;
typedef __attribute__((ext_vector_type(4))) float f32x4;

__device__ inline unsigned short f2b(float f){
    unsigned u = __builtin_bit_cast(unsigned, f);
    u += 0x7fffu + ((u >> 16) & 1u);          // RNE
    return (unsigned short)(u >> 16);
}
__device__ inline float b2f(unsigned short s){
    unsigned u = ((unsigned)s) << 16;
    return __builtin_bit_cast(float, u);
}
__device__ inline float tanh_fast(float x){
    float e = __builtin_amdgcn_exp2f(x * 2.8853900817779268f);
    float r = __builtin_amdgcn_rcpf(e + 1.0f);
    return fmaf(-2.0f, r, 1.0f);
}
__device__ inline void pollge(int* f, int target){
    while (__hip_atomic_load(f, __ATOMIC_RELAXED, __HIP_MEMORY_SCOPE_AGENT) < target)
        __builtin_amdgcn_s_sleep(1);
}

// ---------------- prep: swizzle U (both depths, top/left) + W[1] to bf16 ----
// Bsw[m][kt][c][kk] = M_m[kt*32+kk][c];  m: 0=U0t 1=U0l 2=U1t 3=U1l 4=W1
__global__ __launch_bounds__(256) void prep_kernel(
    const float* __restrict__ U, const float* __restrict__ W,
    unsigned short* __restrict__ Bsw)
{
    int t = blockIdx.x * 256 + threadIdx.x;
    if (t >= 5 * MSZ) return;
    int m  = t >> 16;
    int r  = t & 65535;
    int kt = r >> 13;
    int r2 = r & 8191;
    int c  = r2 >> 5;
    int kk = r2 & 31;
    int krow = kt * 32 + kk;
    float v;
    if (m < 4){ int d = m >> 1, ope = m & 1; v = U[((size_t)d*2*H + ope*H + krow)*H + c]; }
    else      { v = W[((size_t)H + krow)*H + c]; }   // W[1]
    Bsw[t] = f2b(v);
}

// ---------------- depth-0 projections (bf16 out): sxw = src@W0, tyw = trg@W0
__global__ __launch_bounds__(256) void proj0b_kernel(
    const float* __restrict__ src, const float* __restrict__ trg,
    const float* __restrict__ W0, unsigned short* __restrict__ sxw,
    unsigned short* __restrict__ tyw)
{
    const int c = threadIdx.x;
    int gr0 = blockIdx.x * ROWSP;
    const float* inp; unsigned short* outp; int r0;
    if (gr0 < S * B) { inp = src; outp = sxw; r0 = gr0; }
    else             { inp = trg; outp = tyw; r0 = gr0 - S * B; }

    float acc[ROWSP];
#pragma unroll
    for (int rr = 0; rr < ROWSP; ++rr) acc[rr] = 0.f;
    for (int k = 0; k < H; ++k) {
        float wv = W0[k * H + c];
#pragma unroll
        for (int rr = 0; rr < ROWSP; ++rr)
            acc[rr] = fmaf(inp[(size_t)(r0 + rr) * H + k], wv, acc[rr]);
    }
#pragma unroll
    for (int rr = 0; rr < ROWSP; ++rr)
        outp[(size_t)(r0 + rr) * H + c] = f2b(acc[rr]);
}

__global__ __launch_bounds__(256) void zeroflags_kernel(int* flags, int n){
    int t = blockIdx.x * 256 + threadIdx.x;
    if (t < n) flags[t] = 0;
}

// ---------------- persistent dataflow grid kernel (r4: lean sync) ----------
// 128 blocks: blk 0..63 = depth0 (row=blk>>1, colhalf=blk&1), 64..127 = depth1.
// Flags: fx0[cell] (hx0 ready, per half), fy0[cell] (hy0 ready), f1[cell] (hx1).
__global__ __launch_bounds__(512, 2) void grid_kernel(
    const unsigned short* __restrict__ Bsw,
    const unsigned short* __restrict__ sxwb,
    const unsigned short* __restrict__ tywb,
    const float* __restrict__ bvec,
    float* __restrict__ out,
    int* __restrict__ flags)
{
    __shared__ char AldsB[65536];

    const int blk   = blockIdx.x;
    const int depth = blk >> 6;
    const int i     = (blk & 63) >> 1;
    const int ch    = blk & 1;
    const int c0    = ch * 128;

    const int tid  = threadIdx.x;
    const int lane = tid & 63;
    const int wv   = tid >> 6;          // wave 0..7, owns 16 cols
    const int colq = lane & 15;
    const int hi   = lane >> 4;
    const int kk0  = hi * 8;
    const int col  = c0 + wv * 16 + colq;
    const int hi16b = hi * 16;
    const int lswz  = (colq & 7) << 4;  // A-frag read swizzle (A-row&7 == colq&7)

    const int row64 = tid >> 3;         // staging row 0..63
    const int k4b   = (tid & 7) * 4;    // staging float4 base within 32
    const int swz   = (row64 & 7) << 4; // staging write swizzle

    int* fx0 = flags;
    int* fy0 = flags + S*T;
    int* f1  = flags + 2*S*T;

    const size_t CH_ = (size_t)B * H;
#define OPTR(dd,ii,jj,cc) (out + ((((size_t)(dd)*S + (ii))*T + (jj))*2 + (cc)) * CH_)

#define LOAD16(Lp, SP, KC) do { \
    const float* _p = (SP) + (size_t)row64 * H + (KC)*128 + k4b*4; \
    (Lp)[0] = *(const float4*)(_p);      (Lp)[1] = *(const float4*)(_p + 4); \
    (Lp)[2] = *(const float4*)(_p + 8);  (Lp)[3] = *(const float4*)(_p + 12); } while(0)

#define ZERO16(Lp) do { float4 _z = {0.f,0.f,0.f,0.f}; (Lp)[0]=_z;(Lp)[1]=_z;(Lp)[2]=_z;(Lp)[3]=_z; } while(0)

#define WRITE16(BASE, Lp) do { \
    _Pragma("unroll") \
    for (int _l = 0; _l < 4; ++_l) { \
        float4 _v = (Lp)[_l]; uint2 _u; \
        _u.x = f2b(_v.x) | ((unsigned)f2b(_v.y) << 16); \
        _u.y = f2b(_v.z) | ((unsigned)f2b(_v.w) << 16); \
        *(uint2*)(AldsB + (BASE) + row64*256 + (((k4b + _l)*8) ^ swz)) = _u; \
    } } while(0)

#define AFRAG(BASE, RT, KTL) (*(const s16x8*)(AldsB + (BASE) + ((RT)*16 + colq)*256 + ((((KTL)*64) + hi16b) ^ lswz)))

    if (depth == 0) {
        // LDS: [0,16K) leftOwn persistent; [16K,32K) topC0; [32K,48K) topC1; [48K,64K) leftSib
        s16x8 bfT[8], bfL[8];
        {
            const unsigned short* mT = Bsw;
            const unsigned short* mL = Bsw + (size_t)MSZ;
#pragma unroll
            for (int kt = 0; kt < 8; ++kt) {
                int o = (kt * H + col) * 32 + kk0;
                bfT[kt] = *(const s16x8*)(mT + o);
                bfL[kt] = *(const s16x8*)(mL + o);
            }
        }
        const float bb = bvec[col];
        unsigned short xwr[16];
        {
            const unsigned short* xwp = sxwb + (size_t)i * B * H;
#pragma unroll
            for (int rt = 0; rt < 4; ++rt)
#pragma unroll
                for (int q = 0; q < 4; ++q)
                    xwr[rt*4+q] = xwp[(size_t)(rt*16 + hi*4 + q) * H + col];
        }

        for (int j = 0; j < T; ++j) {
            unsigned short ywr[16];
            {
                const unsigned short* ywp = tywb + (size_t)j * B * H;
#pragma unroll
                for (int rt = 0; rt < 4; ++rt)
#pragma unroll
                    for (int q = 0; q < 4; ++q)
                        ywr[rt*4+q] = ywp[(size_t)(rt*16 + hi*4 + q) * H + col];
            }
            if (tid == 0) {
                if (i > 0) pollge(&fx0[(i-1)*T + j], 2);
                if (j > 0) pollge(&fx0[i*T + (j-1)], 2);
                asm volatile("" ::: "memory");
            }
            __syncthreads();

            float4 Lr[12];
            const float* topS = (i > 0) ? OPTR(0, i-1, j, 0) : (const float*)0;
            const float* sibS = (j > 0) ? OPTR(0, i, j-1, 0) : (const float*)0;
            if (topS) { LOAD16(Lr+0, topS, 0); LOAD16(Lr+4, topS, 1); }
            if (sibS) { LOAD16(Lr+8, sibS, 1-ch); }
            if (topS) { WRITE16(16384, Lr+0); WRITE16(32768, Lr+4); }
            if (sibS) { WRITE16(49152, Lr+8); }
            __syncthreads();

            f32x4 acc[4];
#pragma unroll
            for (int rt = 0; rt < 4; ++rt) acc[rt] = (f32x4)(0.f);
            if (topS) {
#pragma unroll
                for (int c = 0; c < 2; ++c) {
                    const int base = c ? 32768 : 16384;
#pragma unroll
                    for (int ktl = 0; ktl < 4; ++ktl)
#pragma unroll
                        for (int rt = 0; rt < 4; ++rt)
                            acc[rt] = __builtin_amdgcn_mfma_f32_16x16x32_bf16(AFRAG(base, rt, ktl), bfT[c*4+ktl], acc[rt], 0, 0, 0);
                }
            }
            if (sibS) {
#pragma unroll
                for (int c = 0; c < 2; ++c) {
                    const int base = (c == ch) ? 0 : 49152;
#pragma unroll
                    for (int ktl = 0; ktl < 4; ++ktl)
#pragma unroll
                        for (int rt = 0; rt < 4; ++rt)
                            acc[rt] = __builtin_amdgcn_mfma_f32_16x16x32_bf16(AFRAG(base, rt, ktl), bfL[c*4+ktl], acc[rt], 0, 0, 0);
                }
            }

            // hx phase (critical chain): tanh, store sc1, drain, flag
            float recv[16]; unsigned short hxb[16];
            float* ox = OPTR(0, i, j, 0);
#pragma unroll
            for (int rt = 0; rt < 4; ++rt)
#pragma unroll
                for (int q = 0; q < 4; ++q) {
                    int idx = rt*4+q;
                    int r = rt*16 + hi*4 + q;
                    float rec = acc[rt][q] + bb;
                    recv[idx] = rec;
                    float hx = tanh_fast(b2f(xwr[idx]) + rec);
                    hxb[idx] = f2b(hx);
                    __hip_atomic_store(&ox[r*H + col], hx, __ATOMIC_RELAXED, __HIP_MEMORY_SCOPE_AGENT);
                }
            asm volatile("s_waitcnt vmcnt(0)" ::: "memory");
            __syncthreads();
            if (tid == 0) __hip_atomic_fetch_add(&fx0[i*T + j], 1, __ATOMIC_RELAXED, __HIP_MEMORY_SCOPE_AGENT);

            // hy phase + leftOwn LDS update (for next j)
            float* oy = OPTR(0, i, j, 1);
#pragma unroll
            for (int rt = 0; rt < 4; ++rt)
#pragma unroll
                for (int q = 0; q < 4; ++q) {
                    int idx = rt*4+q;
                    int r = rt*16 + hi*4 + q;
                    int kkb = (wv*16 + colq) * 2;
                    *(unsigned short*)(AldsB + r*256 + (kkb ^ ((r&7)<<4))) = hxb[idx];
                    float hy = tanh_fast(b2f(ywr[idx]) + recv[idx]);
                    __hip_atomic_store(&oy[r*H + col], hy, __ATOMIC_RELAXED, __HIP_MEMORY_SCOPE_AGENT);
                }
            asm volatile("s_waitcnt vmcnt(0)" ::: "memory");
            __syncthreads();
            if (tid == 0) __hip_atomic_fetch_add(&fy0[i*T + j], 1, __ATOMIC_RELAXED, __HIP_MEMORY_SCOPE_AGENT);
        }
    } else {
        // depth 1: LDS = 4 regions x 16KB: top, left, hx0, hy0 (k-chunked)
        s16x8 bfT[8], bfL[8], bfW[8];
        {
            const unsigned short* mT = Bsw + (size_t)2*MSZ;
            const unsigned short* mL = Bsw + (size_t)3*MSZ;
            const unsigned short* mW = Bsw + (size_t)4*MSZ;
#pragma unroll
            for (int kt = 0; kt < 8; ++kt) {
                int o = (kt * H + col) * 32 + kk0;
                bfT[kt] = *(const s16x8*)(mT + o);
                bfL[kt] = *(const s16x8*)(mL + o);
                bfW[kt] = *(const s16x8*)(mW + o);
            }
        }
        const float bb = bvec[H + col];

        for (int j = 0; j < T; ++j) {
            if (tid == 0) {
                pollge(&fy0[i*T + j], 2);
                if (i > 0) pollge(&f1[(i-1)*T + j], 2);
                if (j > 0) pollge(&f1[i*T + (j-1)], 2);
                asm volatile("" ::: "memory");
            }
            __syncthreads();

            const float* topS = (i > 0) ? OPTR(1, i-1, j, 0) : (const float*)0;
            const float* lftS = (j > 0) ? OPTR(1, i, j-1, 0) : (const float*)0;
            const float* hx0S = OPTR(0, i, j, 0);
            const float* hy0S = OPTR(0, i, j, 1);

            float4 Lr[16];
            if (topS) LOAD16(Lr+0, topS, 0); else ZERO16(Lr+0);
            if (lftS) LOAD16(Lr+4, lftS, 0); else ZERO16(Lr+4);
            LOAD16(Lr+8,  hx0S, 0);
            LOAD16(Lr+12, hy0S, 0);
            WRITE16(0, Lr+0); WRITE16(16384, Lr+4); WRITE16(32768, Lr+8); WRITE16(49152, Lr+12);
            __syncthreads();
            if (topS) LOAD16(Lr+0, topS, 1); else ZERO16(Lr+0);
            if (lftS) LOAD16(Lr+4, lftS, 1); else ZERO16(Lr+4);
            LOAD16(Lr+8,  hx0S, 1);
            LOAD16(Lr+12, hy0S, 1);

            f32x4 ar[4], ax[4], ay[4];
#pragma unroll
            for (int rt = 0; rt < 4; ++rt){ ar[rt]=(f32x4)(0.f); ax[rt]=(f32x4)(0.f); ay[rt]=(f32x4)(0.f); }

#pragma unroll
            for (int ktl = 0; ktl < 4; ++ktl)
#pragma unroll
                for (int rt = 0; rt < 4; ++rt) {
                    if (topS) ar[rt] = __builtin_amdgcn_mfma_f32_16x16x32_bf16(AFRAG(0,    rt, ktl), bfT[ktl], ar[rt], 0, 0, 0);
                    if (lftS) ar[rt] = __builtin_amdgcn_mfma_f32_16x16x32_bf16(AFRAG(16384,rt, ktl), bfL[ktl], ar[rt], 0, 0, 0);
                    ax[rt] = __builtin_amdgcn_mfma_f32_16x16x32_bf16(AFRAG(32768, rt, ktl), bfW[ktl], ax[rt], 0, 0, 0);
                    ay[rt] = __builtin_amdgcn_mfma_f32_16x16x32_bf16(AFRAG(49152, rt, ktl), bfW[ktl], ay[rt], 0, 0, 0);
                }
            __syncthreads();
            WRITE16(0, Lr+0); WRITE16(16384, Lr+4); WRITE16(32768, Lr+8); WRITE16(49152, Lr+12);
            __syncthreads();
#pragma unroll
            for (int ktl = 0; ktl < 4; ++ktl)
#pragma unroll
                for (int rt = 0; rt < 4; ++rt) {
                    if (topS) ar[rt] = __builtin_amdgcn_mfma_f32_16x16x32_bf16(AFRAG(0,    rt, ktl), bfT[4+ktl], ar[rt], 0, 0, 0);
                    if (lftS) ar[rt] = __builtin_amdgcn_mfma_f32_16x16x32_bf16(AFRAG(16384,rt, ktl), bfL[4+ktl], ar[rt], 0, 0, 0);
                    ax[rt] = __builtin_amdgcn_mfma_f32_16x16x32_bf16(AFRAG(32768, rt, ktl), bfW[4+ktl], ax[rt], 0, 0, 0);
                    ay[rt] = __builtin_amdgcn_mfma_f32_16x16x32_bf16(AFRAG(49152, rt, ktl), bfW[4+ktl], ay[rt], 0, 0, 0);
                }

            // hx1 phase (critical chain)
            float recv[16];
            float* ox = OPTR(1, i, j, 0);
#pragma unroll
            for (int rt = 0; rt < 4; ++rt)
#pragma unroll
                for (int q = 0; q < 4; ++q) {
                    int idx = rt*4+q;
                    int r = rt*16 + hi*4 + q;
                    float rec = ar[rt][q] + bb;
                    recv[idx] = rec;
                    float hx = tanh_fast(ax[rt][q] + rec);
                    __hip_atomic_store(&ox[r*H + col], hx, __ATOMIC_RELAXED, __HIP_MEMORY_SCOPE_AGENT);
                }
            asm volatile("s_waitcnt vmcnt(0)" ::: "memory");
            __syncthreads();
            if (tid == 0) __hip_atomic_fetch_add(&f1[i*T + j], 1, __ATOMIC_RELAXED, __HIP_MEMORY_SCOPE_AGENT);

            // hy1: pure output, no one reads it -> no drain, no flag
            float* oy = OPTR(1, i, j, 1);
#pragma unroll
            for (int rt = 0; rt < 4; ++rt)
#pragma unroll
                for (int q = 0; q < 4; ++q) {
                    int idx = rt*4+q;
                    int r = rt*16 + hi*4 + q;
                    float hy = tanh_fast(ay[rt][q] + recv[idx]);
                    __hip_atomic_store(&oy[r*H + col], hy, __ATOMIC_RELAXED, __HIP_MEMORY_SCOPE_AGENT);
                }
        }
    }
#undef OPTR
#undef LOAD16
#undef ZERO16
#undef WRITE16
#undef AFRAG
}

// =================== round-2 staged fallback ===================
__device__ inline s16x8 make_afrag(const float* __restrict__ M, int arow, int k0){
    const float* p = M + arow * H + k0;
    float4 x = *(const float4*)(p);
    float4 y = *(const float4*)(p + 4);
    s16x8 r;
    r[0]=(short)f2b(x.x); r[1]=(short)f2b(x.y); r[2]=(short)f2b(x.z); r[3]=(short)f2b(x.w);
    r[4]=(short)f2b(y.x); r[5]=(short)f2b(y.y); r[6]=(short)f2b(y.z); r[7]=(short)f2b(y.w);
    return r;
}

__global__ __launch_bounds__(64) void stage_kernel(
    const unsigned short* __restrict__ Bsw,
    const unsigned short* __restrict__ sxwb,
    const unsigned short* __restrict__ tywb,
    const float* __restrict__ bvec,
    float* __restrict__ out, int v)
{
    const int lane = threadIdx.x;
    const int cellid = blockIdx.x >> 2;
    const int stripe = blockIdx.x & 3;

    int ilo0 = (v > T-1) ? v-(T-1) : 0, ihi0 = (v < S-1) ? v : S-1;
    int n0 = (v <= S+T-2) ? (ihi0 - ilo0 + 1) : 0;
    if (n0 < 0) n0 = 0;
    int w1 = v - 1;
    int ilo1 = (w1 > T-1) ? w1-(T-1) : 0;

    int d, i, j;
    if (cellid < n0) { d = 0; i = ilo0 + cellid; j = v - i; }
    else             { d = 1; int q = cellid - n0; i = ilo1 + q; j = w1 - i; }

    const int r0   = stripe * 16;
    const int arow = r0 + (lane & 15);
    const int kk0  = (lane >> 4) * 8;
    const int colq = lane & 15;
    const int rowq = r0 + ((lane >> 4) << 2);

#define OUTB(dd,ii,jj,cc) (out + ((((size_t)(dd)*S + (ii))*T + (jj))*2 + (cc)) * (size_t)(B*H))

    if (d == 0) {
        f32x4 acc[16];
#pragma unroll
        for (int t = 0; t < 16; ++t) acc[t] = (f32x4)(0.f);
        if (i > 0) {
            const float* topM = OUTB(0, i-1, j, 0);
            const unsigned short* Bt = Bsw + 0*MSZ;
            for (int kt = 0; kt < 8; ++kt) {
                s16x8 a = make_afrag(topM, arow, kt*32 + kk0);
                const unsigned short* bp = Bt + (kt*H + colq)*32 + kk0;
#pragma unroll
                for (int ct = 0; ct < 16; ++ct)
                    acc[ct] = __builtin_amdgcn_mfma_f32_16x16x32_bf16(a, *(const s16x8*)(bp + ct*512), acc[ct], 0, 0, 0);
            }
        }
        if (j > 0) {
            const float* lftM = OUTB(0, i, j-1, 0);
            const unsigned short* Bl = Bsw + 1*MSZ;
            for (int kt = 0; kt < 8; ++kt) {
                s16x8 a = make_afrag(lftM, arow, kt*32 + kk0);
                const unsigned short* bp = Bl + (kt*H + colq)*32 + kk0;
#pragma unroll
                for (int ct = 0; ct < 16; ++ct)
                    acc[ct] = __builtin_amdgcn_mfma_f32_16x16x32_bf16(a, *(const s16x8*)(bp + ct*512), acc[ct], 0, 0, 0);
            }
        }
        const unsigned short* xwp = sxwb + (size_t)i * B * H;
        const unsigned short* ywp = tywb + (size_t)j * B * H;
        float* ox = OUTB(0, i, j, 0);
        float* oy = OUTB(0, i, j, 1);
#pragma unroll
        for (int ct = 0; ct < 16; ++ct) {
            int col = ct*16 + colq;
            float bc = bvec[col];
#pragma unroll
            for (int q = 0; q < 4; ++q) {
                int row = rowq + q;
                float rec = acc[ct][q] + bc;
                ox[row*H + col] = tanh_fast(b2f(xwp[row*H + col]) + rec);
                oy[row*H + col] = tanh_fast(b2f(ywp[row*H + col]) + rec);
            }
        }
    } else {
        const float* hx0 = OUTB(0, i, j, 0);
        const float* hy0 = OUTB(0, i, j, 1);
        const float* topM = (i > 0) ? OUTB(1, i-1, j, 0) : (const float*)0;
        const float* lftM = (j > 0) ? OUTB(1, i, j-1, 0) : (const float*)0;
        const unsigned short* BU1t = Bsw + 2*MSZ;
        const unsigned short* BU1l = Bsw + 3*MSZ;
        const unsigned short* BW1  = Bsw + 4*MSZ;
        float* ox = OUTB(1, i, j, 0);
        float* oy = OUTB(1, i, j, 1);

        for (int halfc = 0; halfc < 2; ++halfc) {
            f32x4 arr[8], axx[8], ayy[8];
#pragma unroll
            for (int t = 0; t < 8; ++t) { arr[t]=(f32x4)(0.f); axx[t]=(f32x4)(0.f); ayy[t]=(f32x4)(0.f); }
            const int bbase = halfc*4096 + colq*32 + kk0;

            for (int kt = 0; kt < 8; ++kt) {
                const int k0 = kt*32 + kk0;
                const int bofs = kt*H*32 + bbase;
                if (topM) {
                    s16x8 a = make_afrag(topM, arow, k0);
#pragma unroll
                    for (int ct = 0; ct < 8; ++ct)
                        arr[ct] = __builtin_amdgcn_mfma_f32_16x16x32_bf16(a, *(const s16x8*)(BU1t + bofs + ct*512), arr[ct], 0, 0, 0);
                }
                if (lftM) {
                    s16x8 a = make_afrag(lftM, arow, k0);
#pragma unroll
                    for (int ct = 0; ct < 8; ++ct)
                        arr[ct] = __builtin_amdgcn_mfma_f32_16x16x32_bf16(a, *(const s16x8*)(BU1l + bofs + ct*512), arr[ct], 0, 0, 0);
                }
                {
                    s16x8 a = make_afrag(hx0, arow, k0);
#pragma unroll
                    for (int ct = 0; ct < 8; ++ct)
                        axx[ct] = __builtin_amdgcn_mfma_f32_16x16x32_bf16(a, *(const s16x8*)(BW1 + bofs + ct*512), axx[ct], 0, 0, 0);
                }
                {
                    s16x8 a = make_afrag(hy0, arow, k0);
#pragma unroll
                    for (int ct = 0; ct < 8; ++ct)
                        ayy[ct] = __builtin_amdgcn_mfma_f32_16x16x32_bf16(a, *(const s16x8*)(BW1 + bofs + ct*512), ayy[ct], 0, 0, 0);
                }
            }
#pragma unroll
            for (int ct = 0; ct < 8; ++ct) {
                int col = halfc*128 + ct*16 + colq;
                float bc = bvec[H + col];
#pragma unroll
                for (int q = 0; q < 4; ++q) {
                    int row = rowq + q;
                    float rec = arr[ct][q] + bc;
                    ox[row*H + col] = tanh_fast(axx[ct][q] + rec);
                    oy[row*H + col] = tanh_fast(ayy[ct][q] + rec);
                }
            }
        }
    }
#undef OUTB
}

// ============================ host launcher ================================
extern "C" void kernel_launch(void* const* d_in, const int* in_sizes, int n_in,
                              void* d_out, int out_size, void* d_ws, size_t ws_size,
                              hipStream_t stream)
{
    const float* src = (const float*)d_in[0];
    const float* trg = (const float*)d_in[1];
    const float* W   = (const float*)d_in[2];
    const float* U   = (const float*)d_in[3];
    const float* b   = (const float*)d_in[4];
    float* out = (float*)d_out;

    const size_t need_stage   = (size_t)5*MSZ*2 + (size_t)2*S*B*H*2;
    const size_t need_persist = need_stage + (size_t)3*S*T*sizeof(int);

    unsigned short* Bsw  = (unsigned short*)d_ws;
    unsigned short* sxwb = Bsw + (size_t)5*MSZ;
    unsigned short* tywb = sxwb + (size_t)S*B*H;
    int* flags = (int*)(tywb + (size_t)S*B*H);

    if (ws_size >= need_persist) {
        prep_kernel<<<(5*MSZ + 255)/256, 256, 0, stream>>>(U, W, Bsw);
        proj0b_kernel<<<2*S*B/ROWSP, 256, 0, stream>>>(src, trg, W, sxwb, tywb);
        zeroflags_kernel<<<(3*S*T + 255)/256, 256, 0, stream>>>(flags, 3*S*T);
        grid_kernel<<<128, 512, 0, stream>>>(Bsw, sxwb, tywb, b, out, flags);
        return;
    }

    // -------- staged fallback --------
    prep_kernel<<<(5*MSZ + 255)/256, 256, 0, stream>>>(U, W, Bsw);
    proj0b_kernel<<<2*S*B/ROWSP, 256, 0, stream>>>(src, trg, W, sxwb, tywb);
    for (int v = 0; v < S + T; ++v) {
        int ilo0 = (v > T-1) ? v-(T-1) : 0, ihi0 = (v < S-1) ? v : S-1;
        int n0 = (v <= S+T-2) ? (ihi0 - ilo0 + 1) : 0;
        if (n0 < 0) n0 = 0;
        int n1 = 0;
        int w1 = v - 1;
        if (w1 >= 0) {
            int ilo1 = (w1 > T-1) ? w1-(T-1) : 0, ihi1 = (w1 < S-1) ? w1 : S-1;
            n1 = ihi1 - ilo1 + 1;
        }
        stage_kernel<<<4*(n0+n1), 64, 0, stream>>>(Bsw, sxwb, tywb, b, out, v);
    }
}